// Round 2
// baseline (146.190 us; speedup 1.0000x reference)
//
#include <hip/hip_runtime.h>
#include <math.h>

// TopKMoEGate: T = 16384, D = 1024, E = 64, topK = 2.
// Round 7: fused kernel, register-software-pipelined B path.
//  - Round-6 post-mortem: latency-bound (VALUBusy 21%, MfmaUtil 7.6%,
//    HBM 8%); VGPR=52 shows compiler kept nothing in flight -- B loads were
//    consumed same-iteration, eating ~300cy L2 latency x16 chunks.
//  - Fix: explicit s8 b[2][6] double buffer; issue chunk cc+1's B+A loads
//    at the TOP of iteration cc, then split3 convert (pure VALU), then
//    MFMAs consuming b[cc&1] issued a full iteration (~600cy) earlier.
//    No barriers / no LDS in loop -> compiler emits counted vmcnt waits.
//  - Epilogue noise/noise_weight prefetched before the K loop (retire
//    under the loop; removes ~900cy HBM tail).
//  - __launch_bounds__(256,4): cap VGPR at 128 so all 1024 blocks stay
//    co-resident (4 blocks/CU, 16 waves/CU).

#define DDIM 1024
#define NEXP 64
#define NTOK 16384

typedef float f4 __attribute__((ext_vector_type(4)));
typedef short s8 __attribute__((ext_vector_type(8)));
typedef unsigned int u32;

static __device__ __forceinline__ void split3(float f, short& h, short& m, short& l) {
    const u32 uf = __float_as_uint(f);
    h = (short)(uf >> 16);
    const float r1 = f - __uint_as_float(uf & 0xffff0000u);
    const u32 u1 = __float_as_uint(r1);
    m = (short)(u1 >> 16);
    const float r2 = r1 - __uint_as_float(u1 & 0xffff0000u);
    l = (short)(__float_as_uint(r2) >> 16);
}

// ---- kernel 0: slice gate_w into 3 bf16 levels, lane-ordered image ----
// unit16 U'(c,kk,lv,t,q,m) = c*1536 + (kk*3+lv)*256 + t*64 + q*16 + m,
// holding w[e=t*16+m][k0..k0+7], k0 = c*64 + kk*32 + q*8.
__global__ __launch_bounds__(256)
void w_prep(const float* __restrict__ gw, short* __restrict__ wimg) {
    const int uid = blockIdx.x * 256 + threadIdx.x;   // 8192 threads
    const int c   = uid >> 9;
    const int kk  = (uid >> 8) & 1;
    const int e   = (uid >> 2) & 63;
    const int q   = uid & 3;
    const int k0  = c * 64 + kk * 32 + q * 8;
    const float* src = gw + (size_t)e * DDIM + k0;
    s8 hv, mv, lv;
    #pragma unroll
    for (int j = 0; j < 8; ++j) {
        short h, m, l;
        split3(src[j], h, m, l);
        hv[j] = h; mv[j] = m; lv[j] = l;
    }
    const size_t base = (size_t)c * 1536 + (kk * 3) * 256
                      + (e >> 4) * 64 + q * 16 + (e & 15);
    *(s8*)(wimg + (base      ) * 8) = hv;
    *(s8*)(wimg + (base + 256) * 8) = mv;
    *(s8*)(wimg + (base + 512) * 8) = lv;
}

// ---- kernel 1: fused GEMM + noisy top-2 + sparse softmax ----
__global__ __launch_bounds__(256, 4)
void gate_fused(const float* __restrict__ x,
                const short* __restrict__ wimg,
                const float* __restrict__ noise_weight,
                const float* __restrict__ noise,
                float* __restrict__ out_w,
                float* __restrict__ out_i)
{
    __shared__ float L[16][66];                 // [token][expert], padded

    const int tid  = threadIdx.x;
    const int lane = tid & 63;
    const int wv   = tid >> 6;                  // expert tile t = wv
    const int m    = lane & 15;
    const int q    = lane >> 4;
    const int tokBase = blockIdx.x * 16;

    const float* xrow = x + (size_t)(tokBase + m) * DDIM + q * 8;
    const short* wb   = wimg + ((size_t)wv * 64 + lane) * 8;

    // epilogue operands: issue now, retire under the K loop
    const float nw = noise_weight[lane];
    float nz[4];
    #pragma unroll
    for (int tt = 0; tt < 4; ++tt)
        nz[tt] = noise[(size_t)(tokBase + wv * 4 + tt) * NEXP + lane];

    f4 acc0 = (f4)0.f, acc1 = (f4)0.f;

    f4 sa[2][4];                                // A fp32 double buffer
    s8 b[2][6];                                 // B frag double buffer

    // prologue: chunk 0 loads
    sa[0][0] = *(const f4*)(xrow);
    sa[0][1] = *(const f4*)(xrow + 4);
    sa[0][2] = *(const f4*)(xrow + 32);
    sa[0][3] = *(const f4*)(xrow + 36);
    #pragma unroll
    for (int i = 0; i < 6; ++i)
        b[0][i] = *(const s8*)(wb + (size_t)i * (256 * 8));

    #pragma unroll 2
    for (int cc = 0; cc < 16; ++cc) {
        const int cur = cc & 1;
        const int nxt = cur ^ 1;

        // issue next-chunk loads FIRST (consumed next iteration)
        if (cc + 1 < 16) {
            const float* s = xrow + (cc + 1) * 64;
            sa[nxt][0] = *(const f4*)(s);
            sa[nxt][1] = *(const f4*)(s + 4);
            sa[nxt][2] = *(const f4*)(s + 32);
            sa[nxt][3] = *(const f4*)(s + 36);
            const short* p = wb + (size_t)(cc + 1) * (1536 * 8);
            #pragma unroll
            for (int i = 0; i < 6; ++i)
                b[nxt][i] = *(const s8*)(p + (size_t)i * (256 * 8));
        }

        // convert current A chunk -> 3-level bf16 frags (pure VALU)
        s8 ah[2], am_[2], al[2];
        const float* sv = (const float*)sa[cur];
        #pragma unroll
        for (int kk = 0; kk < 2; ++kk)
            #pragma unroll
            for (int j = 0; j < 8; ++j) {
                short h, mm, l;
                split3(sv[kk * 8 + j], h, mm, l);
                ah[kk][j] = h; am_[kk][j] = mm; al[kk][j] = l;
            }

        // 12 MFMAs on b[cur] (issued a full iteration ago)
        acc0 = __builtin_amdgcn_mfma_f32_16x16x32_bf16(ah[0], b[cur][0], acc0, 0, 0, 0);
        acc1 = __builtin_amdgcn_mfma_f32_16x16x32_bf16(ah[0], b[cur][1], acc1, 0, 0, 0);
        acc1 = __builtin_amdgcn_mfma_f32_16x16x32_bf16(am_[0], b[cur][0], acc1, 0, 0, 0);
        acc1 = __builtin_amdgcn_mfma_f32_16x16x32_bf16(ah[0], b[cur][2], acc1, 0, 0, 0);
        acc1 = __builtin_amdgcn_mfma_f32_16x16x32_bf16(am_[0], b[cur][1], acc1, 0, 0, 0);
        acc1 = __builtin_amdgcn_mfma_f32_16x16x32_bf16(al[0], b[cur][0], acc1, 0, 0, 0);

        acc0 = __builtin_amdgcn_mfma_f32_16x16x32_bf16(ah[1], b[cur][3], acc0, 0, 0, 0);
        acc1 = __builtin_amdgcn_mfma_f32_16x16x32_bf16(ah[1], b[cur][4], acc1, 0, 0, 0);
        acc1 = __builtin_amdgcn_mfma_f32_16x16x32_bf16(am_[1], b[cur][3], acc1, 0, 0, 0);
        acc1 = __builtin_amdgcn_mfma_f32_16x16x32_bf16(ah[1], b[cur][5], acc1, 0, 0, 0);
        acc1 = __builtin_amdgcn_mfma_f32_16x16x32_bf16(am_[1], b[cur][4], acc1, 0, 0, 0);
        acc1 = __builtin_amdgcn_mfma_f32_16x16x32_bf16(al[1], b[cur][3], acc1, 0, 0, 0);
    }

    // C layout (round-4/5-verified): lane(q,m), reg r ->
    //   logit[token = tokBase + q*4 + r][expert = m + 16*wv]
    #pragma unroll
    for (int r = 0; r < 4; ++r)
        L[q * 4 + r][m + 16 * wv] = acc0[r] + acc1[r];
    __syncthreads();

    // wave wv handles tokens wv*4 .. wv*4+3; lane = expert (r3-verified)
    #pragma unroll
    for (int tt = 0; tt < 4; ++tt) {
        const int tok  = wv * 4 + tt;
        const int gtok = tokBase + tok;
        const float ln = fmaf(nz[tt], nw, L[tok][lane]);

        float v1 = ln; int i1 = lane;
        #pragma unroll
        for (int off = 32; off > 0; off >>= 1) {
            const float vo = __shfl_xor(v1, off, 64);
            const int   io = __shfl_xor(i1, off, 64);
            if (vo > v1 || (vo == v1 && io < i1)) { v1 = vo; i1 = io; }
        }
        float v2 = (lane == i1) ? -3.4e38f : ln; int i2 = lane;
        #pragma unroll
        for (int off = 32; off > 0; off >>= 1) {
            const float vo = __shfl_xor(v2, off, 64);
            const int   io = __shfl_xor(i2, off, 64);
            if (vo > v2 || (vo == v2 && io < i2)) { v2 = vo; i2 = io; }
        }

        const float d   = expf(v2 - v1);
        const float inv = 1.f / (1.f + d);
        const float wgt = (lane == i1) ? inv : ((lane == i2) ? d * inv : 0.f);
        out_w[(size_t)gtok * NEXP + lane] = wgt;
        if (lane == 0) {
            out_i[(size_t)gtok * 2]     = (float)i1;
            out_i[(size_t)gtok * 2 + 1] = (float)i2;
        }
    }
}

extern "C" void kernel_launch(void* const* d_in, const int* in_sizes, int n_in,
                              void* d_out, int out_size, void* d_ws, size_t ws_size,
                              hipStream_t stream) {
    const float* x     = (const float*)d_in[0];
    const float* gw    = (const float*)d_in[1];
    const float* nwt   = (const float*)d_in[2];
    const float* noise = (const float*)d_in[3];
    float* out_w = (float*)d_out;                        // [NTOK][64]
    float* out_i = (float*)d_out + (size_t)NTOK * NEXP;  // [NTOK][2] as float

    short* wimg = (short*)d_ws;                          // 384 KB image

    hipLaunchKernelGGL(w_prep, dim3(32), dim3(256), 0, stream, gw, wimg);
    hipLaunchKernelGGL(gate_fused, dim3(NTOK / 16), dim3(256), 0, stream,
                       x, wimg, nwt, noise, out_w, out_i);
}

// Round 3
// 144.473 us; speedup vs baseline: 1.0119x; 1.0119x over previous
//
#include <hip/hip_runtime.h>
#include <math.h>

// TopKMoEGate: T = 16384, D = 1024, E = 64, topK = 2.
// Round 8: pin the software pipeline with sched_barrier(0).
//  - Round-7 falsified: VGPR=64 proves the compiler folded the explicit
//    register double-buffer (needs >=120 live) and re-sank loads next to
//    uses -> still latency-bound (VALUBusy 21%, MfmaUtil 7.4%, HBM 8%).
//  - Fix: one __builtin_amdgcn_sched_barrier(0) per half-chunk part. Loads
//    for chunk cc+2 are issued inside part cc and CANNOT sink across the
//    fence into part cc+2 where they're consumed. No inline-asm waitcnt:
//    the compiler's waitcnt pass still sees every load and emits minimal
//    counted vmcnt(N) at first use -> correctness by construction.
//  - VALU cut (bit-identical): pack bf16 pairs with v_perm_b32
//    (__builtin_amdgcn_perm(hi,lo,0x07060302)) instead of per-float
//    shift/or packing. Same truncation math, same MFMA order.
//  - Full unroll: all buffer indices compile-time (no scratch).

#define DDIM 1024
#define NEXP 64
#define NTOK 16384

typedef float f4 __attribute__((ext_vector_type(4)));
typedef short s8 __attribute__((ext_vector_type(8)));
typedef unsigned int u32;

static __device__ __forceinline__ void split3(float f, short& h, short& m, short& l) {
    const u32 uf = __float_as_uint(f);
    h = (short)(uf >> 16);
    const float r1 = f - __uint_as_float(uf & 0xffff0000u);
    const u32 u1 = __float_as_uint(r1);
    m = (short)(u1 >> 16);
    const float r2 = r1 - __uint_as_float(u1 & 0xffff0000u);
    l = (short)(__float_as_uint(r2) >> 16);
}

// ---- kernel 0: slice gate_w into 3 bf16 levels, lane-ordered image ----
// unit16 U'(c,kk,lv,t,q,m) = c*1536 + (kk*3+lv)*256 + t*64 + q*16 + m,
// holding w[e=t*16+m][k0..k0+7], k0 = c*64 + kk*32 + q*8.
__global__ __launch_bounds__(256)
void w_prep(const float* __restrict__ gw, short* __restrict__ wimg) {
    const int uid = blockIdx.x * 256 + threadIdx.x;   // 8192 threads
    const int c   = uid >> 9;
    const int kk  = (uid >> 8) & 1;
    const int e   = (uid >> 2) & 63;
    const int q   = uid & 3;
    const int k0  = c * 64 + kk * 32 + q * 8;
    const float* src = gw + (size_t)e * DDIM + k0;
    s8 hv, mv, lv;
    #pragma unroll
    for (int j = 0; j < 8; ++j) {
        short h, m, l;
        split3(src[j], h, m, l);
        hv[j] = h; mv[j] = m; lv[j] = l;
    }
    const size_t base = (size_t)c * 1536 + (kk * 3) * 256
                      + (e >> 4) * 64 + q * 16 + (e & 15);
    *(s8*)(wimg + (base      ) * 8) = hv;
    *(s8*)(wimg + (base + 256) * 8) = mv;
    *(s8*)(wimg + (base + 512) * 8) = lv;
}

// pack hi 16 bits of (flo, fhi) -> u32 {lo16 = hi(flo), hi16 = hi(fhi)}
static __device__ __forceinline__ u32 packhi(float flo, float fhi) {
    return __builtin_amdgcn_perm(__float_as_uint(fhi), __float_as_uint(flo),
                                 0x07060302u);
}

union FragU { u32 u[4]; s8 v; };

// convert 8 consecutive floats -> 3-level bf16 frags (h, m, l)
static __device__ __forceinline__ void conv8(const float* f, s8& h, s8& m, s8& l) {
    FragU H, M, L;
    #pragma unroll
    for (int j = 0; j < 4; ++j) {
        const float f0 = f[2 * j], f1 = f[2 * j + 1];
        H.u[j] = packhi(f0, f1);
        const float g0 = f0 - __uint_as_float(__float_as_uint(f0) & 0xffff0000u);
        const float g1 = f1 - __uint_as_float(__float_as_uint(f1) & 0xffff0000u);
        M.u[j] = packhi(g0, g1);
        const float e0 = g0 - __uint_as_float(__float_as_uint(g0) & 0xffff0000u);
        const float e1 = g1 - __uint_as_float(__float_as_uint(g1) & 0xffff0000u);
        L.u[j] = packhi(e0, e1);
    }
    h = H.v; m = M.v; l = L.v;
}

#define MF(A, B, C) __builtin_amdgcn_mfma_f32_16x16x32_bf16((A), (B), (C), 0, 0, 0)

#define LOADA(S, P) { const float* _a = (P);                \
    S[0] = *(const f4*)(_a);      S[1] = *(const f4*)(_a + 4);  \
    S[2] = *(const f4*)(_a + 32); S[3] = *(const f4*)(_a + 36); }

#define LOADB(B, P) { const short* _b = (P);                \
    B[0] = *(const s8*)(_b);         B[1] = *(const s8*)(_b + 2048); \
    B[2] = *(const s8*)(_b + 4096);  B[3] = *(const s8*)(_b + 6144); \
    B[4] = *(const s8*)(_b + 8192);  B[5] = *(const s8*)(_b + 10240); }

// one half-chunk part: consume set (SA,SB) for its current chunk, then
// reissue the set for chunk NC; fence so the reissue can't sink onward.
#define PART(SA, SB, NC)                                              \
  {                                                                   \
    s8 ah0, am0, al0, ah1, am1, al1;                                  \
    conv8((const float*)&SA[0], ah0, am0, al0);                       \
    conv8((const float*)&SA[2], ah1, am1, al1);                       \
    if ((NC) < 16) LOADA(SA, xrow + (NC) * 64);                       \
    acc0 = MF(ah0, SB[0], acc0);  acc1 = MF(ah0, SB[1], acc1);        \
    acc1 = MF(am0, SB[0], acc1);  acc1 = MF(ah0, SB[2], acc1);        \
    acc1 = MF(am0, SB[1], acc1);  acc1 = MF(al0, SB[0], acc1);        \
    acc0 = MF(ah1, SB[3], acc0);  acc1 = MF(ah1, SB[4], acc1);        \
    acc1 = MF(am1, SB[3], acc1);  acc1 = MF(ah1, SB[5], acc1);        \
    acc1 = MF(am1, SB[4], acc1);  acc1 = MF(al1, SB[3], acc1);        \
    if ((NC) < 16) LOADB(SB, wb + (size_t)(NC) * 12288);              \
    __builtin_amdgcn_sched_barrier(0);                                \
  }

// ---- kernel 1: fused GEMM + noisy top-2 + sparse softmax ----
__global__ __launch_bounds__(256, 3)
void gate_fused(const float* __restrict__ x,
                const short* __restrict__ wimg,
                const float* __restrict__ noise_weight,
                const float* __restrict__ noise,
                float* __restrict__ out_w,
                float* __restrict__ out_i)
{
    __shared__ float Lds[16][66];               // [token][expert], padded

    const int tid  = threadIdx.x;
    const int lane = tid & 63;
    const int wv   = tid >> 6;                  // expert tile t = wv
    const int m    = lane & 15;
    const int q    = lane >> 4;
    const int tokBase = blockIdx.x * 16;

    const float* xrow = x + (size_t)(tokBase + m) * DDIM + q * 8;
    const short* wb   = wimg + ((size_t)wv * 64 + lane) * 8;

    // epilogue operands: issue now, retire under the K loop
    const float nw = noise_weight[lane];
    float nz[4];
    #pragma unroll
    for (int tt = 0; tt < 4; ++tt)
        nz[tt] = noise[(size_t)(tokBase + wv * 4 + tt) * NEXP + lane];

    f4 acc0 = (f4)0.f, acc1 = (f4)0.f;

    f4 sa0[4], sa1[4];                          // A fp32 double buffer
    s8 b0[6], b1[6];                            // B frag double buffer

    // prologue: chunks 0 and 1
    LOADA(sa0, xrow);           LOADB(b0, wb);
    LOADA(sa1, xrow + 64);      LOADB(b1, wb + 12288);
    __builtin_amdgcn_sched_barrier(0);

    #pragma unroll
    for (int cc = 0; cc < 16; cc += 2) {
        PART(sa0, b0, cc + 2);
        PART(sa1, b1, cc + 3);
    }

    // C layout (round-4/5-verified): lane(q,m), reg r ->
    //   logit[token = tokBase + q*4 + r][expert = m + 16*wv]
    #pragma unroll
    for (int r = 0; r < 4; ++r)
        Lds[q * 4 + r][m + 16 * wv] = acc0[r] + acc1[r];
    __syncthreads();

    // wave wv handles tokens wv*4 .. wv*4+3; lane = expert (r3-verified)
    #pragma unroll
    for (int tt = 0; tt < 4; ++tt) {
        const int tok  = wv * 4 + tt;
        const int gtok = tokBase + tok;
        const float ln = fmaf(nz[tt], nw, Lds[tok][lane]);

        float v1 = ln; int i1 = lane;
        #pragma unroll
        for (int off = 32; off > 0; off >>= 1) {
            const float vo = __shfl_xor(v1, off, 64);
            const int   io = __shfl_xor(i1, off, 64);
            if (vo > v1 || (vo == v1 && io < i1)) { v1 = vo; i1 = io; }
        }
        float v2 = (lane == i1) ? -3.4e38f : ln; int i2 = lane;
        #pragma unroll
        for (int off = 32; off > 0; off >>= 1) {
            const float vo = __shfl_xor(v2, off, 64);
            const int   io = __shfl_xor(i2, off, 64);
            if (vo > v2 || (vo == v2 && io < i2)) { v2 = vo; i2 = io; }
        }

        const float d   = expf(v2 - v1);
        const float inv = 1.f / (1.f + d);
        const float wgt = (lane == i1) ? inv : ((lane == i2) ? d * inv : 0.f);
        out_w[(size_t)gtok * NEXP + lane] = wgt;
        if (lane == 0) {
            out_i[(size_t)gtok * 2]     = (float)i1;
            out_i[(size_t)gtok * 2 + 1] = (float)i2;
        }
    }
}

extern "C" void kernel_launch(void* const* d_in, const int* in_sizes, int n_in,
                              void* d_out, int out_size, void* d_ws, size_t ws_size,
                              hipStream_t stream) {
    const float* x     = (const float*)d_in[0];
    const float* gw    = (const float*)d_in[1];
    const float* nwt   = (const float*)d_in[2];
    const float* noise = (const float*)d_in[3];
    float* out_w = (float*)d_out;                        // [NTOK][64]
    float* out_i = (float*)d_out + (size_t)NTOK * NEXP;  // [NTOK][2] as float

    short* wimg = (short*)d_ws;                          // 384 KB image

    hipLaunchKernelGGL(w_prep, dim3(32), dim3(256), 0, stream, gw, wimg);
    hipLaunchKernelGGL(gate_fused, dim3(NTOK / 16), dim3(256), 0, stream,
                       x, wimg, nwt, noise, out_w, out_i);
}

// Round 4
// 126.820 us; speedup vs baseline: 1.1527x; 1.1392x over previous
//
#include <hip/hip_runtime.h>
#include <math.h>

// TopKMoEGate: T = 16384, D = 1024, E = 64, topK = 2.
// Round 9: fused kernel with round-5's sharing geometry restored.
//  - Rounds 6-8 all ~63 us regardless of register pipelining: the 16-token
//    block re-read the full 384 KB B-image per block (393 MB of sync L2
//    reads) and duplicated A-conversion 4x. Latency-bound by structure.
//  - This round: block = 4 waves over 32 tokens x full K x full E.
//    Wave (ts,eh) = (token-half, expert-half): B chunk shared by all
//    4 waves (197 MB L2 traffic), A-conv duplicated only 2x, no split-K
//    partials. B staged via round-5-verified global_load_lds image path,
//    DOUBLE-buffered: one __syncthreads per chunk; DMA+A-loads for c+1
//    issued right after the barrier publishing c (pinned by
//    sched_barrier(0)), in flight during compute(c).
//  - Epilogue fused: logits -> 8.4 KB LDS tile (expert-split => disjoint
//    writes, no reduce), then r3-verified butterfly top-2 + softmax.
//  - LDS 57.6 KB/block -> 2 blocks/CU; grid 512 = 2/CU exactly.

#define DDIM 1024
#define NEXP 64
#define NTOK 16384

typedef float f4 __attribute__((ext_vector_type(4)));
typedef short s8 __attribute__((ext_vector_type(8)));
typedef unsigned int u32;

static __device__ __forceinline__ void split3(float f, short& h, short& m, short& l) {
    const u32 uf = __float_as_uint(f);
    h = (short)(uf >> 16);
    const float r1 = f - __uint_as_float(uf & 0xffff0000u);
    const u32 u1 = __float_as_uint(r1);
    m = (short)(u1 >> 16);
    const float r2 = r1 - __uint_as_float(u1 & 0xffff0000u);
    l = (short)(__float_as_uint(r2) >> 16);
}

static __device__ __forceinline__ void gl_lds16(const void* g, void* l) {
    __builtin_amdgcn_global_load_lds(
        (const __attribute__((address_space(1))) u32*)g,
        (__attribute__((address_space(3))) u32*)l, 16, 0, 0);
}

// ---- kernel 0: slice gate_w into 3 bf16 levels, lane-ordered image ----
// unit16 U'(c,kk,lv,t,q,m) = c*1536 + (kk*3+lv)*256 + t*64 + q*16 + m,
// holding w[e=t*16+m][k0..k0+7], k0 = c*64 + kk*32 + q*8.  24 KB per chunk.
__global__ __launch_bounds__(256)
void w_prep(const float* __restrict__ gw, short* __restrict__ wimg) {
    const int uid = blockIdx.x * 256 + threadIdx.x;   // 8192 threads
    const int c   = uid >> 9;
    const int kk  = (uid >> 8) & 1;
    const int e   = (uid >> 2) & 63;
    const int q   = uid & 3;
    const int k0  = c * 64 + kk * 32 + q * 8;
    const float* src = gw + (size_t)e * DDIM + k0;
    s8 hv, mv, lv;
    #pragma unroll
    for (int j = 0; j < 8; ++j) {
        short h, m, l;
        split3(src[j], h, m, l);
        hv[j] = h; mv[j] = m; lv[j] = l;
    }
    const size_t base = (size_t)c * 1536 + (kk * 3) * 256
                      + (e >> 4) * 64 + q * 16 + (e & 15);
    *(s8*)(wimg + (base      ) * 8) = hv;
    *(s8*)(wimg + (base + 256) * 8) = mv;
    *(s8*)(wimg + (base + 512) * 8) = lv;
}

// pack hi 16 bits of (flo, fhi) -> u32 {lo16 = hi(flo), hi16 = hi(fhi)}
static __device__ __forceinline__ u32 packhi(float flo, float fhi) {
    return __builtin_amdgcn_perm(__float_as_uint(fhi), __float_as_uint(flo),
                                 0x07060302u);
}

union FragU { u32 u[4]; s8 v; };

// convert 8 consecutive floats -> 3-level bf16 frags (h, m, l)  [r8-verified]
static __device__ __forceinline__ void conv8(const float* f, s8& h, s8& m, s8& l) {
    FragU H, M, L;
    #pragma unroll
    for (int j = 0; j < 4; ++j) {
        const float f0 = f[2 * j], f1 = f[2 * j + 1];
        H.u[j] = packhi(f0, f1);
        const float g0 = f0 - __uint_as_float(__float_as_uint(f0) & 0xffff0000u);
        const float g1 = f1 - __uint_as_float(__float_as_uint(f1) & 0xffff0000u);
        M.u[j] = packhi(g0, g1);
        const float e0 = g0 - __uint_as_float(__float_as_uint(g0) & 0xffff0000u);
        const float e1 = g1 - __uint_as_float(__float_as_uint(g1) & 0xffff0000u);
        L.u[j] = packhi(e0, e1);
    }
    h = H.v; m = M.v; l = L.v;
}

#define MF(A, B, C) __builtin_amdgcn_mfma_f32_16x16x32_bf16((A), (B), (C), 0, 0, 0)

// ---- kernel 1: fused GEMM + noisy top-2 + sparse softmax ----
__global__ __launch_bounds__(256, 2)
void gate_fused(const float* __restrict__ x,
                const short* __restrict__ wimg,
                const float* __restrict__ noise_weight,
                const float* __restrict__ noise,
                float* __restrict__ out_w,
                float* __restrict__ out_i)
{
    __shared__ short bs[2][1536 * 8];           // 2 x 24 KB B chunk buffers
    __shared__ float Lds[32][66];               // [token][expert], padded

    const int tid  = threadIdx.x;
    const int lane = tid & 63;
    const int wv   = tid >> 6;
    const int m    = lane & 15;
    const int q    = lane >> 4;
    const int ts   = wv & 1;                    // token half (16 tokens)
    const int eh   = wv >> 1;                   // expert half (32 experts)
    const int tokBase = blockIdx.x * 32;

    const float* xrow = x + (size_t)(tokBase + ts * 16 + m) * DDIM + q * 8;
    const int t64a = (eh * 2 + 0) * 64;         // image unit offsets of the
    const int t64b = (eh * 2 + 1) * 64;         //   wave's two expert tiles

    // epilogue operands: issue now, retire under the K loop
    const float nw = noise_weight[lane];
    float nz[8];
    #pragma unroll
    for (int tt = 0; tt < 8; ++tt)
        nz[tt] = noise[(size_t)(tokBase + wv * 8 + tt) * NEXP + lane];

    f4 accA0 = (f4)0.f, accB0 = (f4)0.f;        // expert tile eh*2
    f4 accA1 = (f4)0.f, accB1 = (f4)0.f;        // expert tile eh*2+1

    f4 sa0[4], sa1[4];                          // A fp32 double buffer

#define STAGE(BUF, C) {                                              \
    const short* _c = wimg + (size_t)(C) * 12288;                    \
    _Pragma("unroll")                                                \
    for (int _i = 0; _i < 6; ++_i) {                                 \
        const int _off = (wv * 6 + _i) * 512;                        \
        gl_lds16(_c + _off + lane * 8, &bs[BUF][_off]);              \
    } }

#define LOADA(S, C) { const float* _a = xrow + (C) * 64;             \
    S[0] = *(const f4*)(_a);      S[1] = *(const f4*)(_a + 4);       \
    S[2] = *(const f4*)(_a + 32); S[3] = *(const f4*)(_a + 36); }

// consume one k64 chunk from bs[BUF] with A regs SA (verified mappings)
#define COMPUTE(BUF, SA) {                                           \
    s8 ah0, am0, al0, ah1, am1, al1;                                 \
    conv8((const float*)&SA[0], ah0, am0, al0);                      \
    conv8((const float*)&SA[2], ah1, am1, al1);                      \
    { const int p = t64a + lane;                                     \
      const s8 bh = *(const s8*)&bs[BUF][(p       ) * 8];            \
      const s8 bm = *(const s8*)&bs[BUF][(p +  256) * 8];            \
      const s8 bl = *(const s8*)&bs[BUF][(p +  512) * 8];            \
      accA0 = MF(ah0, bh, accA0);  accB0 = MF(ah0, bm, accB0);       \
      accB0 = MF(am0, bh, accB0);  accB0 = MF(ah0, bl, accB0);       \
      accB0 = MF(am0, bm, accB0);  accB0 = MF(al0, bh, accB0); }     \
    { const int p = t64b + lane;                                     \
      const s8 bh = *(const s8*)&bs[BUF][(p       ) * 8];            \
      const s8 bm = *(const s8*)&bs[BUF][(p +  256) * 8];            \
      const s8 bl = *(const s8*)&bs[BUF][(p +  512) * 8];            \
      accA1 = MF(ah0, bh, accA1);  accB1 = MF(ah0, bm, accB1);       \
      accB1 = MF(am0, bh, accB1);  accB1 = MF(ah0, bl, accB1);       \
      accB1 = MF(am0, bm, accB1);  accB1 = MF(al0, bh, accB1); }     \
    { const int p = 768 + t64a + lane;                               \
      const s8 bh = *(const s8*)&bs[BUF][(p       ) * 8];            \
      const s8 bm = *(const s8*)&bs[BUF][(p +  256) * 8];            \
      const s8 bl = *(const s8*)&bs[BUF][(p +  512) * 8];            \
      accA0 = MF(ah1, bh, accA0);  accB0 = MF(ah1, bm, accB0);       \
      accB0 = MF(am1, bh, accB0);  accB0 = MF(ah1, bl, accB0);       \
      accB0 = MF(am1, bm, accB0);  accB0 = MF(al1, bh, accB0); }     \
    { const int p = 768 + t64b + lane;                               \
      const s8 bh = *(const s8*)&bs[BUF][(p       ) * 8];            \
      const s8 bm = *(const s8*)&bs[BUF][(p +  256) * 8];            \
      const s8 bl = *(const s8*)&bs[BUF][(p +  512) * 8];            \
      accA1 = MF(ah1, bh, accA1);  accB1 = MF(ah1, bm, accB1);       \
      accB1 = MF(am1, bh, accB1);  accB1 = MF(ah1, bl, accB1);       \
      accB1 = MF(am1, bm, accB1);  accB1 = MF(al1, bh, accB1); }     \
  }

    // prologue: chunk 0 in flight
    STAGE(0, 0);
    LOADA(sa0, 0);

    #pragma unroll
    for (int c = 0; c < 16; c += 2) {
        __syncthreads();                        // publishes chunk c (buf0)
        STAGE(1, c + 1);                        // DMA chunk c+1 under compute
        LOADA(sa1, c + 1);
        __builtin_amdgcn_sched_barrier(0);      // pin issue point
        COMPUTE(0, sa0);

        __syncthreads();                        // publishes chunk c+1 (buf1)
        if (c + 2 < 16) {
            STAGE(0, c + 2);
            LOADA(sa0, c + 2);
        }
        __builtin_amdgcn_sched_barrier(0);
        COMPUTE(1, sa1);
    }

    // C layout (verified): lane(q,m), reg r ->
    //   logit[token = ts*16 + q*4 + r][expert = m + 16*tile]
    #pragma unroll
    for (int r = 0; r < 4; ++r) {
        Lds[ts * 16 + q * 4 + r][m + 16 * (eh * 2 + 0)] = accA0[r] + accB0[r];
        Lds[ts * 16 + q * 4 + r][m + 16 * (eh * 2 + 1)] = accA1[r] + accB1[r];
    }
    __syncthreads();

    // wave wv handles tokens wv*8 .. wv*8+7; lane = expert (r3-verified)
    #pragma unroll
    for (int tt = 0; tt < 8; ++tt) {
        const int tok  = wv * 8 + tt;
        const int gtok = tokBase + tok;
        const float ln = fmaf(nz[tt], nw, Lds[tok][lane]);

        float v1 = ln; int i1 = lane;
        #pragma unroll
        for (int off = 32; off > 0; off >>= 1) {
            const float vo = __shfl_xor(v1, off, 64);
            const int   io = __shfl_xor(i1, off, 64);
            if (vo > v1 || (vo == v1 && io < i1)) { v1 = vo; i1 = io; }
        }
        float v2 = (lane == i1) ? -3.4e38f : ln; int i2 = lane;
        #pragma unroll
        for (int off = 32; off > 0; off >>= 1) {
            const float vo = __shfl_xor(v2, off, 64);
            const int   io = __shfl_xor(i2, off, 64);
            if (vo > v2 || (vo == v2 && io < i2)) { v2 = vo; i2 = io; }
        }

        const float d   = expf(v2 - v1);
        const float inv = 1.f / (1.f + d);
        const float wgt = (lane == i1) ? inv : ((lane == i2) ? d * inv : 0.f);
        out_w[(size_t)gtok * NEXP + lane] = wgt;
        if (lane == 0) {
            out_i[(size_t)gtok * 2]     = (float)i1;
            out_i[(size_t)gtok * 2 + 1] = (float)i2;
        }
    }
}

extern "C" void kernel_launch(void* const* d_in, const int* in_sizes, int n_in,
                              void* d_out, int out_size, void* d_ws, size_t ws_size,
                              hipStream_t stream) {
    const float* x     = (const float*)d_in[0];
    const float* gw    = (const float*)d_in[1];
    const float* nwt   = (const float*)d_in[2];
    const float* noise = (const float*)d_in[3];
    float* out_w = (float*)d_out;                        // [NTOK][64]
    float* out_i = (float*)d_out + (size_t)NTOK * NEXP;  // [NTOK][2] as float

    short* wimg = (short*)d_ws;                          // 384 KB image

    hipLaunchKernelGGL(w_prep, dim3(32), dim3(256), 0, stream, gw, wimg);
    hipLaunchKernelGGL(gate_fused, dim3(NTOK / 32), dim3(256), 0, stream,
                       x, wimg, nwt, noise, out_w, out_i);
}